// Round 1
// baseline (171.006 us; speedup 1.0000x reference)
//
#include <hip/hip_runtime.h>

#define FEAT 64

// row_start[n] = lower_bound(edge_dst, n); edge_dst is sorted.
__global__ void build_rowptr(const int* __restrict__ edge_dst, int E, int N,
                             int* __restrict__ row_start) {
    int n = blockIdx.x * blockDim.x + threadIdx.x;
    if (n > N) return;
    int lo = 0, hi = E;
    while (lo < hi) {
        int mid = (lo + hi) >> 1;
        if (edge_dst[mid] < n) lo = mid + 1; else hi = mid;
    }
    row_start[n] = lo;
}

// One wave per destination node; lane = feature dim (0..63).
// Writes out[n,0:64] = features[n], out[n,64:128] = agg1[n].
__global__ void hop1(const float* __restrict__ feat,
                     const int* __restrict__ edge_src,
                     const int* __restrict__ row_start,
                     float* __restrict__ out, int N) {
    int wave = (blockIdx.x * blockDim.x + threadIdx.x) >> 6;
    int lane = threadIdx.x & 63;
    if (wave >= N) return;
    int n = wave;
    int s = row_start[n];
    int e = row_start[n + 1];
    float acc = 0.f;
    for (int i = s; i < e; ++i) {
        int src = edge_src[i];
        acc += feat[src * FEAT + lane];
    }
    float deg = (float)((e - s) > 0 ? (e - s) : 1);
    out[n * 256 + lane]       = feat[n * FEAT + lane];
    out[n * 256 + 64 + lane]  = acc / deg;
}

// One wave per node; each lane covers h1 dims (lane) and (lane+64).
// h1[src] = (features[src, 0:64], out[src, 64:128]).
// Writes out[n,128:256] = agg2[n].
__global__ void hop2(const float* __restrict__ feat,
                     const int* __restrict__ edge_src,
                     const int* __restrict__ row_start,
                     float* __restrict__ out, int N) {
    int wave = (blockIdx.x * blockDim.x + threadIdx.x) >> 6;
    int lane = threadIdx.x & 63;
    if (wave >= N) return;
    int n = wave;
    int s = row_start[n];
    int e = row_start[n + 1];
    float acc0 = 0.f, acc1 = 0.f;
    for (int i = s; i < e; ++i) {
        int src = edge_src[i];
        acc0 += feat[src * FEAT + lane];       // h1 dims 0..63
        acc1 += out[src * 256 + 64 + lane];    // h1 dims 64..127 (agg1)
    }
    float deg = (float)((e - s) > 0 ? (e - s) : 1);
    out[n * 256 + 128 + lane] = acc0 / deg;
    out[n * 256 + 192 + lane] = acc1 / deg;
}

extern "C" void kernel_launch(void* const* d_in, const int* in_sizes, int n_in,
                              void* d_out, int out_size, void* d_ws, size_t ws_size,
                              hipStream_t stream) {
    const float* feat     = (const float*)d_in[0];
    const int*   edge_src = (const int*)d_in[1];
    const int*   edge_dst = (const int*)d_in[2];
    float*       out      = (float*)d_out;
    int*         row_start = (int*)d_ws;   // N+1 ints

    int N = in_sizes[0] / FEAT;
    int E = in_sizes[1];

    build_rowptr<<<(N + 256) / 256, 256, 0, stream>>>(edge_dst, E, N, row_start);
    // 4 waves (nodes) per 256-thread block
    hop1<<<(N + 3) / 4, 256, 0, stream>>>(feat, edge_src, row_start, out, N);
    hop2<<<(N + 3) / 4, 256, 0, stream>>>(feat, edge_src, row_start, out, N);
}

// Round 2
// 79.562 us; speedup vs baseline: 2.1493x; 2.1493x over previous
//
#include <hip/hip_runtime.h>

#define FEAT 64

// row_start[n] = lower_bound(edge_dst, n); edge_dst is sorted.
__global__ void build_rowptr(const int* __restrict__ edge_dst, int E, int N,
                             int* __restrict__ row_start) {
    int n = blockIdx.x * blockDim.x + threadIdx.x;
    if (n > N) return;
    int lo = 0, hi = E;
    while (lo < hi) {
        int mid = (lo + hi) >> 1;
        if (edge_dst[mid] < n) lo = mid + 1; else hi = mid;
    }
    row_start[n] = lo;
}

// One wave per destination node.
// Lane decomposition: eg = lane>>4 (edge slot, 4 edges in flight),
//                     fq = lane&15 (float4 chunk of the 64-dim row).
// Writes out[n,0:64]=feat[n], out[n,64:128]=agg1[n], out[n,128:192]=agg1[n]
// (since agg2[:,0:64] == agg1 algebraically).
__global__ void __launch_bounds__(256) hop1(
        const float* __restrict__ feat,
        const int* __restrict__ edge_src,
        const int* __restrict__ row_start,
        float* __restrict__ out, int N) {
    int wave = (blockIdx.x * blockDim.x + threadIdx.x) >> 6;
    if (wave >= N) return;
    int lane = threadIdx.x & 63;
    int eg = lane >> 4;
    int fq = lane & 15;
    int s = row_start[wave];
    int e = row_start[wave + 1];

    float4 acc = make_float4(0.f, 0.f, 0.f, 0.f);
    for (int i = s + eg; i < e; i += 4) {
        int src = edge_src[i];
        const float4 v = *(const float4*)(feat + (size_t)src * FEAT + fq * 4);
        acc.x += v.x; acc.y += v.y; acc.z += v.z; acc.w += v.w;
    }
    // reduce the 4 edge-group partials (lanes l, l^16, l^32, l^48)
    #pragma unroll
    for (int m = 16; m <= 32; m <<= 1) {
        acc.x += __shfl_xor(acc.x, m, 64);
        acc.y += __shfl_xor(acc.y, m, 64);
        acc.z += __shfl_xor(acc.z, m, 64);
        acc.w += __shfl_xor(acc.w, m, 64);
    }
    float inv = 1.0f / (float)((e - s) > 0 ? (e - s) : 1);
    acc.x *= inv; acc.y *= inv; acc.z *= inv; acc.w *= inv;

    float* orow = out + (size_t)wave * 256;
    if (eg == 0) {
        float4 f = *(const float4*)(feat + (size_t)wave * FEAT + fq * 4);
        *(float4*)(orow + fq * 4) = f;                 // cols 0:64 = features
    } else if (eg == 1) {
        *(float4*)(orow + 64 + fq * 4) = acc;          // cols 64:128 = agg1
    } else if (eg == 2) {
        *(float4*)(orow + 128 + fq * 4) = acc;         // cols 128:192 = agg1 (== agg2[:,0:64])
    }
}

// One wave per node; gathers ONLY the agg1 slice (out[src,64:128]) and
// writes out[n,192:256] = mean_nbr(agg1).
__global__ void __launch_bounds__(256) hop2(
        const int* __restrict__ edge_src,
        const int* __restrict__ row_start,
        float* __restrict__ out, int N) {
    int wave = (blockIdx.x * blockDim.x + threadIdx.x) >> 6;
    if (wave >= N) return;
    int lane = threadIdx.x & 63;
    int eg = lane >> 4;
    int fq = lane & 15;
    int s = row_start[wave];
    int e = row_start[wave + 1];

    float4 acc = make_float4(0.f, 0.f, 0.f, 0.f);
    for (int i = s + eg; i < e; i += 4) {
        int src = edge_src[i];
        const float4 v = *(const float4*)(out + (size_t)src * 256 + 64 + fq * 4);
        acc.x += v.x; acc.y += v.y; acc.z += v.z; acc.w += v.w;
    }
    #pragma unroll
    for (int m = 16; m <= 32; m <<= 1) {
        acc.x += __shfl_xor(acc.x, m, 64);
        acc.y += __shfl_xor(acc.y, m, 64);
        acc.z += __shfl_xor(acc.z, m, 64);
        acc.w += __shfl_xor(acc.w, m, 64);
    }
    float inv = 1.0f / (float)((e - s) > 0 ? (e - s) : 1);
    acc.x *= inv; acc.y *= inv; acc.z *= inv; acc.w *= inv;

    if (eg == 0) {
        *(float4*)(out + (size_t)wave * 256 + 192 + fq * 4) = acc;
    }
}

extern "C" void kernel_launch(void* const* d_in, const int* in_sizes, int n_in,
                              void* d_out, int out_size, void* d_ws, size_t ws_size,
                              hipStream_t stream) {
    const float* feat     = (const float*)d_in[0];
    const int*   edge_src = (const int*)d_in[1];
    const int*   edge_dst = (const int*)d_in[2];
    float*       out      = (float*)d_out;
    int*         row_start = (int*)d_ws;   // N+1 ints

    int N = in_sizes[0] / FEAT;
    int E = in_sizes[1];

    build_rowptr<<<(N + 256) / 256, 256, 0, stream>>>(edge_dst, E, N, row_start);
    hop1<<<(N + 3) / 4, 256, 0, stream>>>(feat, edge_src, row_start, out, N);
    hop2<<<(N + 3) / 4, 256, 0, stream>>>(edge_src, row_start, out, N);
}

// Round 3
// 68.552 us; speedup vs baseline: 2.4945x; 1.1606x over previous
//
#include <hip/hip_runtime.h>

#define FEAT 64

static __device__ __forceinline__ unsigned short f2bf(float f) {
    unsigned u = __float_as_uint(f);
    unsigned r = (u + 0x7FFF + ((u >> 16) & 1)) >> 16;   // round-to-nearest-even
    return (unsigned short)r;
}
static __device__ __forceinline__ float bf_lo(unsigned u) {   // low ushort -> float
    return __uint_as_float(u << 16);
}
static __device__ __forceinline__ float bf_hi(unsigned u) {   // high ushort -> float
    return __uint_as_float(u & 0xffff0000u);
}

// Convert features to bf16 (compact [N,64] in ws). One thread per 4 floats.
__global__ void feat_to_bf16(const float* __restrict__ feat,
                             unsigned short* __restrict__ fb, int total4) {
    int i = blockIdx.x * blockDim.x + threadIdx.x;
    if (i >= total4) return;
    float4 v = ((const float4*)feat)[i];
    ushort4 o;
    o.x = f2bf(v.x); o.y = f2bf(v.y); o.z = f2bf(v.z); o.w = f2bf(v.w);
    ((ushort4*)fb)[i] = o;
}

// row_start[n] = lower_bound(edge_dst, n); edge_dst is sorted.
__global__ void build_rowptr(const int* __restrict__ edge_dst, int E, int N,
                             int* __restrict__ row_start) {
    int n = blockIdx.x * blockDim.x + threadIdx.x;
    if (n > N) return;
    int lo = 0, hi = E;
    while (lo < hi) {
        int mid = (lo + hi) >> 1;
        if (edge_dst[mid] < n) lo = mid + 1; else hi = mid;
    }
    row_start[n] = lo;
}

// One wave per destination node.
// eg = lane>>3 (8 edges in flight), fq = lane&7 (16B chunk = 8 bf16 of the row).
// Writes: out[n,0:64]=feat f32, out[n,64:128]=agg1, out[n,128:192]=agg1
// (agg2[:,0:64]==agg1 algebraically), and agg1 as bf16 into ws for hop2.
__global__ void __launch_bounds__(256) hop1(
        const float* __restrict__ feat,
        const unsigned short* __restrict__ fb,
        const int* __restrict__ edge_src,
        const int* __restrict__ row_start,
        float* __restrict__ out,
        unsigned short* __restrict__ agg1b, int N) {
    int wave = (blockIdx.x * blockDim.x + threadIdx.x) >> 6;
    if (wave >= N) return;
    int lane = threadIdx.x & 63;
    int eg = lane >> 3;
    int fq = lane & 7;
    int s = row_start[wave];
    int e = row_start[wave + 1];

    float acc[8] = {0.f, 0.f, 0.f, 0.f, 0.f, 0.f, 0.f, 0.f};
    for (int i = s + eg; i < e; i += 8) {
        int src = edge_src[i];
        uint4 p = *(const uint4*)(fb + (size_t)src * FEAT + fq * 8);
        acc[0] += bf_lo(p.x); acc[1] += bf_hi(p.x);
        acc[2] += bf_lo(p.y); acc[3] += bf_hi(p.y);
        acc[4] += bf_lo(p.z); acc[5] += bf_hi(p.z);
        acc[6] += bf_lo(p.w); acc[7] += bf_hi(p.w);
    }
    #pragma unroll
    for (int m = 8; m <= 32; m <<= 1) {
        #pragma unroll
        for (int k = 0; k < 8; ++k) acc[k] += __shfl_xor(acc[k], m, 64);
    }
    float inv = 1.0f / (float)((e - s) > 0 ? (e - s) : 1);
    #pragma unroll
    for (int k = 0; k < 8; ++k) acc[k] *= inv;

    float* orow = out + (size_t)wave * 256;
    if (eg == 0) {            // cols 64:128 = agg1
        *(float4*)(orow + 64 + fq * 8)     = make_float4(acc[0], acc[1], acc[2], acc[3]);
        *(float4*)(orow + 64 + fq * 8 + 4) = make_float4(acc[4], acc[5], acc[6], acc[7]);
    } else if (eg == 1) {     // cols 128:192 = agg1 (== agg2[:,0:64])
        *(float4*)(orow + 128 + fq * 8)     = make_float4(acc[0], acc[1], acc[2], acc[3]);
        *(float4*)(orow + 128 + fq * 8 + 4) = make_float4(acc[4], acc[5], acc[6], acc[7]);
    } else if (eg == 2) {     // cols 0:64 = features (f32 copy)
        float4 f0 = *(const float4*)(feat + (size_t)wave * FEAT + fq * 8);
        float4 f1 = *(const float4*)(feat + (size_t)wave * FEAT + fq * 8 + 4);
        *(float4*)(orow + fq * 8)     = f0;
        *(float4*)(orow + fq * 8 + 4) = f1;
    } else if (eg == 3) {     // agg1 bf16 -> ws for hop2's gather
        uint4 pk;
        pk.x = (unsigned)f2bf(acc[0]) | ((unsigned)f2bf(acc[1]) << 16);
        pk.y = (unsigned)f2bf(acc[2]) | ((unsigned)f2bf(acc[3]) << 16);
        pk.z = (unsigned)f2bf(acc[4]) | ((unsigned)f2bf(acc[5]) << 16);
        pk.w = (unsigned)f2bf(acc[6]) | ((unsigned)f2bf(acc[7]) << 16);
        *(uint4*)(agg1b + (size_t)wave * FEAT + fq * 8) = pk;
    }
}

// One wave per node; gathers bf16 agg1 from ws, writes out[n,192:256] f32.
__global__ void __launch_bounds__(256) hop2(
        const unsigned short* __restrict__ agg1b,
        const int* __restrict__ edge_src,
        const int* __restrict__ row_start,
        float* __restrict__ out, int N) {
    int wave = (blockIdx.x * blockDim.x + threadIdx.x) >> 6;
    if (wave >= N) return;
    int lane = threadIdx.x & 63;
    int eg = lane >> 3;
    int fq = lane & 7;
    int s = row_start[wave];
    int e = row_start[wave + 1];

    float acc[8] = {0.f, 0.f, 0.f, 0.f, 0.f, 0.f, 0.f, 0.f};
    for (int i = s + eg; i < e; i += 8) {
        int src = edge_src[i];
        uint4 p = *(const uint4*)(agg1b + (size_t)src * FEAT + fq * 8);
        acc[0] += bf_lo(p.x); acc[1] += bf_hi(p.x);
        acc[2] += bf_lo(p.y); acc[3] += bf_hi(p.y);
        acc[4] += bf_lo(p.z); acc[5] += bf_hi(p.z);
        acc[6] += bf_lo(p.w); acc[7] += bf_hi(p.w);
    }
    #pragma unroll
    for (int m = 8; m <= 32; m <<= 1) {
        #pragma unroll
        for (int k = 0; k < 8; ++k) acc[k] += __shfl_xor(acc[k], m, 64);
    }
    float inv = 1.0f / (float)((e - s) > 0 ? (e - s) : 1);
    #pragma unroll
    for (int k = 0; k < 8; ++k) acc[k] *= inv;

    if (eg == 0) {
        float* orow = out + (size_t)wave * 256;
        *(float4*)(orow + 192 + fq * 8)     = make_float4(acc[0], acc[1], acc[2], acc[3]);
        *(float4*)(orow + 192 + fq * 8 + 4) = make_float4(acc[4], acc[5], acc[6], acc[7]);
    }
}

extern "C" void kernel_launch(void* const* d_in, const int* in_sizes, int n_in,
                              void* d_out, int out_size, void* d_ws, size_t ws_size,
                              hipStream_t stream) {
    const float* feat     = (const float*)d_in[0];
    const int*   edge_src = (const int*)d_in[1];
    const int*   edge_dst = (const int*)d_in[2];
    float*       out      = (float*)d_out;

    int N = in_sizes[0] / FEAT;
    int E = in_sizes[1];

    // ws layout (16B-aligned segments): fb16 [N*64 ushort], agg1b [N*64 ushort],
    // row_start [N+1 int]
    unsigned short* fb16  = (unsigned short*)d_ws;
    unsigned short* agg1b = fb16 + (size_t)N * FEAT;
    int* row_start        = (int*)(agg1b + (size_t)N * FEAT);

    int total4 = N * FEAT / 4;
    feat_to_bf16<<<(total4 + 255) / 256, 256, 0, stream>>>(feat, fb16, total4);
    build_rowptr<<<(N + 256) / 256, 256, 0, stream>>>(edge_dst, E, N, row_start);
    hop1<<<(N + 3) / 4, 256, 0, stream>>>(feat, fb16, edge_src, row_start, out, agg1b, N);
    hop2<<<(N + 3) / 4, 256, 0, stream>>>(agg1b, edge_src, row_start, out, N);
}